// Round 1
// 249.688 us; speedup vs baseline: 1.0071x; 1.0071x over previous
//
#include <hip/hip_runtime.h>
#include <hip/hip_bf16.h>

// ExpertBank MoE FFN on gfx950 — round 10.
// r9 counters: k_gemm2d 77us with MfmaUtil 8.7 / VALU 4 / HBM 23% / Occ 24% -> latency-bound.
// Fix: T3 minimum 2-phase pipeline in both GEMMs — double-buffered LDS tiles, stage(next)
// issued BEFORE compute(cur), raw s_barrier + asm vmcnt(0) (NOT __syncthreads, whose
// vmcnt-drain would serialize the prefetch). sched_barrier(0) pins MFMA cluster before the
// wait (rule 18-adjacent: prevents compile-time sinking past the buffer-overwrite point).
// Also: W2 transpose folded into k_prep when ws_size allows a separate W2T buffer
// (58.85MB -> 75.6MB); runtime fallback to the r4-proven WT-reuse + k_tw2 path.
// ws: int[0..7] counts, [16..23] opad, [32..) rowmap(9216),
//     byte 65536: H bf16 [9216][2048] (37.75 MB), Xb bf16 (4.2 MB),
//     W1T bf16 (16.8 MB), [optional] W2T bf16 (16.8 MB).

typedef __bf16 bf16x8 __attribute__((ext_vector_type(8)));
typedef float f32x4 __attribute__((ext_vector_type(4)));

#define DM 512
#define DF 2048
#define NE 8
#define NTOK 4096
#define NPAIR 8192
#define HCAP 9216

__device__ __forceinline__ unsigned short f2bf(float x) {
    unsigned u = __builtin_bit_cast(unsigned, x);
    return (unsigned short)((u + 0x7fffu + ((u >> 16) & 1u)) >> 16);
}
__device__ __forceinline__ unsigned pack2(float lo, float hi) {
    return (unsigned)f2bf(lo) | ((unsigned)f2bf(hi) << 16);
}
__device__ __forceinline__ float gelu_fast(float x) {
    // tanh-form GELU via exp: |err| <= ~3e-4 absolute, negligible vs bf16 path
    float y = 0.7978845608028654f * (x + 0.044715f * x * x * x);
    float e = __expf(2.0f * y);
    float t = 1.0f - 2.0f / (e + 1.0f);
    return 0.5f * x * (1.0f + t);
}
// async 16B global->LDS (gfx950); lds pointer must be wave-uniform, writes lane*16B
__device__ __forceinline__ void dma16(const unsigned short* g, unsigned short* l) {
    __builtin_amdgcn_global_load_lds(
        (const __attribute__((address_space(1))) void*)g,
        (__attribute__((address_space(3))) void*)l, 16, 0, 0);
}
// swizzled 16B-slot index for (row, q) in an unpadded [rows][32] bf16 tile
__device__ __forceinline__ int slot_of(int row, int q) {
    return row * 4 + (q ^ ((row >> 1) & 3));
}

// one 128x128x32 MFMA step from swizzled LDS tiles
__device__ __forceinline__ void mfma_tile(const unsigned short* Ab, const unsigned short* Bb,
                                          int wm, int wn, int quad, int l15,
                                          f32x4 (&acc)[4][4]) {
    bf16x8 a[4], b[4];
#pragma unroll
    for (int fm = 0; fm < 4; ++fm)
        a[fm] = __builtin_bit_cast(bf16x8, *(const uint4*)&Ab[slot_of(wm * 64 + fm * 16 + l15, quad) * 8]);
#pragma unroll
    for (int fn = 0; fn < 4; ++fn)
        b[fn] = __builtin_bit_cast(bf16x8, *(const uint4*)&Bb[slot_of(wn * 64 + fn * 16 + l15, quad) * 8]);
#pragma unroll
    for (int fm = 0; fm < 4; ++fm)
#pragma unroll
        for (int fn = 0; fn < 4; ++fn)
            acc[fm][fn] = __builtin_amdgcn_mfma_f32_16x16x32_bf16(a[fm], b[fn], acc[fm][fn], 0, 0, 0);
}

#define STAGE(buf, ko)                                   \
    do {                                                 \
        _Pragma("unroll") for (int j = 0; j < 2; ++j) {  \
            dma16(ga[j] + (ko), la[j] + (buf) * 4096);   \
            dma16(gb[j] + (ko), lb[j] + (buf) * 4096);   \
        }                                                \
    } while (0)

#define PIPE_WAIT()                                      \
    do {                                                 \
        __builtin_amdgcn_sched_barrier(0);               \
        asm volatile("s_waitcnt vmcnt(0)" ::: "memory"); \
        __builtin_amdgcn_s_barrier();                    \
    } while (0)

// ---- mega-prep: [0,1024) cvtX, [1024,3072) tw(W1), [3072,5120) zero out, 5120 routing,
// ----            [5121,7169) tw(W2)  (only dispatched in fused mode) ----
__global__ void k_prep(const float* __restrict__ X, unsigned short* __restrict__ Xb,
                       const float* __restrict__ W1, unsigned short* __restrict__ W1T,
                       const float* __restrict__ W2, unsigned short* __restrict__ W2T,
                       float* __restrict__ outz,
                       const int* __restrict__ sel, int* __restrict__ counts_g,
                       int* __restrict__ opad_g, int* __restrict__ rowmap,
                       float* __restrict__ loads_out) {
    __shared__ unsigned short T[64][65];
    __shared__ int hist[NE], cur[NE], off[NE];
    const int b = blockIdx.x, tid = threadIdx.x;

    if (b < 1024) {  // X fp32 -> bf16
        int i = (b * 256 + tid) * 8;
        float4 a = *(const float4*)(X + i);
        float4 c = *(const float4*)(X + i + 4);
        uint4 u;
        u.x = pack2(a.x, a.y); u.y = pack2(a.z, a.w);
        u.z = pack2(c.x, c.y); u.w = pack2(c.z, c.w);
        *(uint4*)(Xb + i) = u;
    } else if (b < 3072) {  // W1 [E][DM][DF] -> bf16 W1T [E][DF][DM]
        const int t = b - 1024;
        const int bx = t & 31, by = (t >> 5) & 7, bz = t >> 8;
        const int tx = tid & 15, ty = tid >> 4;
        const int r0 = by * 64, c0 = bx * 64;
        const float* src = W1 + ((size_t)bz * DM + r0) * DF + c0;
#pragma unroll
        for (int i = 0; i < 4; ++i) {
            int r = ty + i * 16;
            float4 v = *(const float4*)(src + (size_t)r * DF + tx * 4);
            T[tx * 4 + 0][r] = f2bf(v.x); T[tx * 4 + 1][r] = f2bf(v.y);
            T[tx * 4 + 2][r] = f2bf(v.z); T[tx * 4 + 3][r] = f2bf(v.w);
        }
        __syncthreads();
        unsigned short* dst = W1T + ((size_t)bz * DF + c0) * DM + r0;
#pragma unroll
        for (int i = 0; i < 4; ++i) {
            int c = ty + i * 16;
            ushort4 w;
            w.x = T[c][tx * 4 + 0]; w.y = T[c][tx * 4 + 1];
            w.z = T[c][tx * 4 + 2]; w.w = T[c][tx * 4 + 3];
            *(ushort4*)(dst + (size_t)c * DM + tx * 4) = w;
        }
    } else if (b < 5120) {  // zero expert_outputs (gemm2 atomics accumulate into it)
        size_t i = ((size_t)(b - 3072) * 256 + tid) * 8;
        float4 z = make_float4(0.f, 0.f, 0.f, 0.f);
        *(float4*)(outz + i) = z;
        *(float4*)(outz + i + 4) = z;
    } else if (b == 5120) {  // routing: histogram + padded scan + compact assign
        if (tid < NE) { hist[tid] = 0; cur[tid] = 0; }
        __syncthreads();
#pragma unroll
        for (int i = 0; i < NPAIR / 256; ++i)
            atomicAdd(&hist[sel[i * 256 + tid]], 1);
        __syncthreads();
        if (tid == 0) {
            int s = 0;
            for (int e = 0; e < NE; ++e) {
                off[e] = s;
                s += (hist[e] + 127) & ~127;
                counts_g[e] = hist[e];
                opad_g[e] = off[e];
                loads_out[e] = (float)hist[e] * (1.0f / (float)NTOK);
            }
        }
        __syncthreads();
#pragma unroll
        for (int i = 0; i < NPAIR / 256; ++i) {
            int p = i * 256 + tid;
            int e = sel[p];
            int pos = atomicAdd(&cur[e], 1);
            rowmap[off[e] + pos] = p;
        }
    } else {  // W2 [E][DF][DM] -> bf16 W2T [E][DM][DF] (fused mode only)
        const int t = b - 5121;
        const int bx = t & 7, by = (t >> 3) & 31, bz = t >> 8;
        const int tx = tid & 15, ty = tid >> 4;
        const int r0 = by * 64, c0 = bx * 64;
        const float* src = W2 + ((size_t)bz * DF + r0) * DM + c0;
#pragma unroll
        for (int i = 0; i < 4; ++i) {
            int r = ty + i * 16;
            float4 v = *(const float4*)(src + (size_t)r * DM + tx * 4);
            T[tx * 4 + 0][r] = f2bf(v.x); T[tx * 4 + 1][r] = f2bf(v.y);
            T[tx * 4 + 2][r] = f2bf(v.z); T[tx * 4 + 3][r] = f2bf(v.w);
        }
        __syncthreads();
        unsigned short* dst = W2T + ((size_t)bz * DM + c0) * DF + r0;
#pragma unroll
        for (int i = 0; i < 4; ++i) {
            int c = ty + i * 16;
            ushort4 w;
            w.x = T[c][tx * 4 + 0]; w.y = T[c][tx * 4 + 1];
            w.z = T[c][tx * 4 + 2]; w.w = T[c][tx * 4 + 3];
            *(ushort4*)(dst + (size_t)c * DF + tx * 4) = w;
        }
    }
}

// ---- W2 [E][DF][DM] -> bf16 W2T [E][DM][DF] (fallback when ws too small to fuse) ----
__global__ void k_tw2(const float* __restrict__ in, unsigned short* __restrict__ out) {
    __shared__ unsigned short T[64][65];
    const int tid = threadIdx.x;
    const int tx = tid & 15, ty = tid >> 4;
    const int r0 = blockIdx.y * 64, c0 = blockIdx.x * 64;
    const float* src = in + ((size_t)blockIdx.z * DF + r0) * DM + c0;
#pragma unroll
    for (int i = 0; i < 4; ++i) {
        int r = ty + i * 16;
        float4 v = *(const float4*)(src + (size_t)r * DM + tx * 4);
        T[tx * 4 + 0][r] = f2bf(v.x); T[tx * 4 + 1][r] = f2bf(v.y);
        T[tx * 4 + 2][r] = f2bf(v.z); T[tx * 4 + 3][r] = f2bf(v.w);
    }
    __syncthreads();
    unsigned short* dst = out + ((size_t)blockIdx.z * DM + c0) * DF + r0;
#pragma unroll
    for (int i = 0; i < 4; ++i) {
        int c = ty + i * 16;
        ushort4 w;
        w.x = T[c][tx * 4 + 0]; w.y = T[c][tx * 4 + 1];
        w.z = T[c][tx * 4 + 2]; w.w = T[c][tx * 4 + 3];
        *(ushort4*)(dst + (size_t)c * DF + tx * 4) = w;
    }
}

// ---------------- GEMM1: H = gelu(Xb[tok] @ W1), 128x128, BK=32, 2-phase dbuf --------
__launch_bounds__(256, 4)
__global__ void k_gemm1d(const unsigned short* __restrict__ Xb,
                         const unsigned short* __restrict__ W1T,
                         const int* __restrict__ counts, const int* __restrict__ opad,
                         const int* __restrict__ rowmap, unsigned short* __restrict__ H) {
    const int e = blockIdx.z, mt = blockIdx.y, nt = blockIdx.x;
    const int grow = opad[e] + mt * 128;
    int valid = counts[e] - mt * 128;
    if (valid <= 0) return;
    if (valid > 128) valid = 128;

    __shared__ __align__(16) unsigned short As[2][128 * 32];
    __shared__ __align__(16) unsigned short Bs[2][128 * 32];
    __shared__ int toks[128];

    const int tid = threadIdx.x;
    if (tid < 128) {
        int i = (tid < valid) ? tid : 0;
        toks[tid] = rowmap[grow + i] >> 1;
    }
    __syncthreads();

    const int wave = tid >> 6, lane = tid & 63;
    const int wm = wave >> 1, wn = wave & 1;
    const int quad = lane >> 4, l15 = lane & 15;

    // per-lane DMA source pointers for the 2 A-issues and 2 B-issues of this wave
    const unsigned short* ga[2];
    const unsigned short* gb[2];
    unsigned short* la[2];
    unsigned short* lb[2];
#pragma unroll
    for (int j = 0; j < 2; ++j) {
        int slot = wave * 128 + j * 64 + lane;
        int row = slot >> 2;
        int q = (slot & 3) ^ ((row >> 1) & 3);
        ga[j] = Xb + (size_t)toks[row] * DM + q * 8;
        gb[j] = W1T + ((size_t)e * DF + nt * 128 + row) * DM + q * 8;
        la[j] = &As[0][(wave * 128 + j * 64) * 8];
        lb[j] = &Bs[0][(wave * 128 + j * 64) * 8];
    }

    f32x4 acc[4][4] = {};

    // 2-phase pipeline: stage(next) issued before compute(cur); raw barrier + vmcnt(0)
    STAGE(0, 0);
    PIPE_WAIT();
#pragma unroll 1
    for (int kt = 0; kt < DM / 32; kt += 2) {
        if (kt + 1 < DM / 32) STAGE(1, (kt + 1) * 32);
        mfma_tile(&As[0][0], &Bs[0][0], wm, wn, quad, l15, acc);
        PIPE_WAIT();
        if (kt + 2 < DM / 32) STAGE(0, (kt + 2) * 32);
        mfma_tile(&As[1][0], &Bs[1][0], wm, wn, quad, l15, acc);
        PIPE_WAIT();
    }

#pragma unroll
    for (int fm = 0; fm < 4; ++fm) {
#pragma unroll
        for (int i = 0; i < 4; ++i) {
            int m_l = wm * 64 + fm * 16 + quad * 4 + i;
            if (m_l < valid) {
                unsigned short* hrow = H + (size_t)(grow + m_l) * DF + nt * 128 + wn * 64;
#pragma unroll
                for (int fn = 0; fn < 4; ++fn)
                    hrow[fn * 16 + l15] = f2bf(gelu_fast(acc[fm][fn][i]));
            }
        }
    }
}

// ---------------- GEMM2: out += H @ W2, 128x128, split-K x4, 2-phase dbuf ------------
__launch_bounds__(256, 4)
__global__ void k_gemm2d(const unsigned short* __restrict__ H,
                         const unsigned short* __restrict__ W2T,
                         const int* __restrict__ counts, const int* __restrict__ opad,
                         const int* __restrict__ rowmap, float* __restrict__ out) {
    const int e = blockIdx.z, mt = blockIdx.y;
    const int nt = blockIdx.x & 3, ks = blockIdx.x >> 2;
    const int grow = opad[e] + mt * 128;
    int valid = counts[e] - mt * 128;
    if (valid <= 0) return;
    if (valid > 128) valid = 128;

    __shared__ __align__(16) unsigned short As[2][128 * 32];
    __shared__ __align__(16) unsigned short Bs[2][128 * 32];
    __shared__ int pairs[128];

    const int tid = threadIdx.x;
    if (tid < 128) pairs[tid] = (tid < valid) ? rowmap[grow + tid] : 0;
    __syncthreads();

    const int wave = tid >> 6, lane = tid & 63;
    const int wm = wave >> 1, wn = wave & 1;
    const int quad = lane >> 4, l15 = lane & 15;

    const unsigned short* ga[2];
    const unsigned short* gb[2];
    unsigned short* la[2];
    unsigned short* lb[2];
#pragma unroll
    for (int j = 0; j < 2; ++j) {
        int slot = wave * 128 + j * 64 + lane;
        int row = slot >> 2;
        int q = (slot & 3) ^ ((row >> 1) & 3);
        int rr = (row < valid) ? row : 0;  // clamp: never read unwritten H (r7 lesson)
        ga[j] = H + (size_t)(grow + rr) * DF + ks * 512 + q * 8;
        gb[j] = W2T + ((size_t)e * DM + nt * 128 + row) * DF + ks * 512 + q * 8;
        la[j] = &As[0][(wave * 128 + j * 64) * 8];
        lb[j] = &Bs[0][(wave * 128 + j * 64) * 8];
    }

    f32x4 acc[4][4] = {};

    STAGE(0, 0);
    PIPE_WAIT();
#pragma unroll 1
    for (int kt = 0; kt < 16; kt += 2) {
        if (kt + 1 < 16) STAGE(1, (kt + 1) * 32);
        mfma_tile(&As[0][0], &Bs[0][0], wm, wn, quad, l15, acc);
        PIPE_WAIT();
        if (kt + 2 < 16) STAGE(0, (kt + 2) * 32);
        mfma_tile(&As[1][0], &Bs[1][0], wm, wn, quad, l15, acc);
        PIPE_WAIT();
    }

#pragma unroll
    for (int fm = 0; fm < 4; ++fm) {
#pragma unroll
        for (int i = 0; i < 4; ++i) {
            int m_l = wm * 64 + fm * 16 + quad * 4 + i;
            if (m_l < valid) {
                float* orow = out + (size_t)pairs[m_l] * DM + nt * 128 + wn * 64;
#pragma unroll
                for (int fn = 0; fn < 4; ++fn)
                    atomicAdd(&orow[fn * 16 + l15], acc[fm][fn][i]);
            }
        }
    }
}

extern "C" void kernel_launch(void* const* d_in, const int* in_sizes, int n_in,
                              void* d_out, int out_size, void* d_ws, size_t ws_size,
                              hipStream_t stream) {
    const float* X = (const float*)d_in[0];
    const int* sel = (const int*)d_in[1];
    const float* W1 = (const float*)d_in[3];
    const float* W2 = (const float*)d_in[4];
    float* out = (float*)d_out;
    float* loads_out = out + (size_t)NPAIR * DM;

    int* counts = (int*)d_ws;
    int* opad = counts + 16;
    int* rowmap = counts + 32;
    const size_t hbytes = (size_t)HCAP * DF * 2;
    const size_t xbytes = (size_t)NTOK * DM * 2;
    const size_t w1tbytes = (size_t)NE * DF * DM * 2;
    unsigned short* H = (unsigned short*)((char*)d_ws + 65536);
    unsigned short* Xb = (unsigned short*)((char*)d_ws + 65536 + hbytes);
    unsigned short* WT = (unsigned short*)((char*)d_ws + 65536 + hbytes + xbytes);

    // fused mode: separate W2T buffer -> W2 transpose folds into k_prep, no k_tw2 dispatch
    const bool fused = ws_size >= 65536 + hbytes + xbytes + 2 * w1tbytes;
    unsigned short* W2T = fused ? WT + w1tbytes / 2 : WT;

    hipLaunchKernelGGL(k_prep, dim3(fused ? 7169 : 5121), dim3(256), 0, stream,
                       X, Xb, W1, WT, W2, W2T, out, sel, counts, opad, rowmap, loads_out);
    hipLaunchKernelGGL(k_gemm1d, dim3(DF / 128, NPAIR / 128, NE), dim3(256), 0, stream,
                       Xb, WT, counts, opad, rowmap, H);
    if (!fused)
        hipLaunchKernelGGL(k_tw2, dim3(DM / 64, DF / 64, NE), dim3(256), 0, stream, W2, WT);
    hipLaunchKernelGGL(k_gemm2d, dim3(16, NPAIR / 128, NE), dim3(256), 0, stream,
                       H, W2T, counts, opad, rowmap, out);
}

// Round 3
// 223.480 us; speedup vs baseline: 1.1252x; 1.1173x over previous
//
#include <hip/hip_runtime.h>
#include <hip/hip_bf16.h>

// ExpertBank MoE FFN on gfx950 — round 12 (r11 + compile fix: out2_dst inlined).
// r10 post-mortem: 2-phase pipeline was a no-op (80us, MfmaUtil 8.7%) -> K-loop is NOT
// latency-bound. Diagnosis: BK=32 tile rows are 64B, so every global_load_lds covers 16
// scattered 64B (sub-cache-line) segments -> ~4.2M L2 requests per GEMM -> request-rate
// bound (~55us), matching both GEMMs. Fix: BK=64 (rows = 128B = full line, 2x fewer /
// 2x larger requests), swizzle re-derived (chunk^(row&7), pre-swizzled GLOBAL source per
// m173 since global_load_lds writes linearly), double-buffer with counted vmcnt(8) (T4 —
// prefetch never drained), launch_bounds(256,2) @ 66KB LDS. gemm2: split-K 4->2 (atomics
// halve to 8.3M; 512 working blocks = 2/CU residency).
// ws: int[0..7] counts, [16..23] opad, [32..) rowmap(9216),
//     byte 65536: H bf16 [9216][2048] (37.75 MB), Xb bf16 (4.2 MB),
//     W1T bf16 (16.8 MB), [optional] W2T bf16 (16.8 MB).

typedef __bf16 bf16x8 __attribute__((ext_vector_type(8)));
typedef float f32x4 __attribute__((ext_vector_type(4)));

#define DM 512
#define DF 2048
#define NE 8
#define NTOK 4096
#define NPAIR 8192
#define HCAP 9216

__device__ __forceinline__ unsigned short f2bf(float x) {
    unsigned u = __builtin_bit_cast(unsigned, x);
    return (unsigned short)((u + 0x7fffu + ((u >> 16) & 1u)) >> 16);
}
__device__ __forceinline__ unsigned pack2(float lo, float hi) {
    return (unsigned)f2bf(lo) | ((unsigned)f2bf(hi) << 16);
}
__device__ __forceinline__ float gelu_fast(float x) {
    // tanh-form GELU via exp: |err| <= ~3e-4 absolute, negligible vs bf16 path
    float y = 0.7978845608028654f * (x + 0.044715f * x * x * x);
    float e = __expf(2.0f * y);
    float t = 1.0f - 2.0f / (e + 1.0f);
    return 0.5f * x * (1.0f + t);
}
// async 16B global->LDS (gfx950); lds pointer must be wave-uniform, writes lane*16B
__device__ __forceinline__ void dma16(const unsigned short* g, unsigned short* l) {
    __builtin_amdgcn_global_load_lds(
        (const __attribute__((address_space(1))) void*)g,
        (__attribute__((address_space(3))) void*)l, 16, 0, 0);
}
// BK=64 tile [128][64] bf16: 8 16B-chunks per 128B row; XOR swizzle chunk^(row&7).
// Read side: lanes 0..15 hit 8 distinct chunk slots x2 rows = 2-way bank alias = free.
__device__ __forceinline__ int slot64(int row, int c) { return row * 8 + (c ^ (row & 7)); }

// one 128x128x64 MFMA step (2 x K=32 sub-steps) from swizzled LDS tiles
__device__ __forceinline__ void mfma_step(const unsigned short* Ab, const unsigned short* Bb,
                                          int wm, int wn, int quad, int l15,
                                          f32x4 (&acc)[4][4]) {
#pragma unroll
    for (int kk = 0; kk < 2; ++kk) {
        const int c = kk * 4 + quad;
        bf16x8 a[4], b[4];
#pragma unroll
        for (int fm = 0; fm < 4; ++fm) {
            int row = wm * 64 + fm * 16 + l15;
            a[fm] = __builtin_bit_cast(bf16x8, *(const uint4*)&Ab[slot64(row, c) * 8]);
        }
#pragma unroll
        for (int fn = 0; fn < 4; ++fn) {
            int row = wn * 64 + fn * 16 + l15;
            b[fn] = __builtin_bit_cast(bf16x8, *(const uint4*)&Bb[slot64(row, c) * 8]);
        }
#pragma unroll
        for (int fm = 0; fm < 4; ++fm)
#pragma unroll
            for (int fn = 0; fn < 4; ++fn)
                acc[fm][fn] = __builtin_amdgcn_mfma_f32_16x16x32_bf16(a[fm], b[fn], acc[fm][fn], 0, 0, 0);
    }
}

// 8 dma16 per wave per STAGE (4 A + 4 B); ko in ushort elements; buf stride 8192 ushorts
#define STAGE(buf, ko)                                        \
    do {                                                      \
        _Pragma("unroll") for (int j_ = 0; j_ < 4; ++j_) {    \
            dma16(ga[j_] + (ko), la[j_] + (buf) * 8192);      \
            dma16(gb[j_] + (ko), lb[j_] + (buf) * 8192);      \
        }                                                     \
    } while (0)

#define WAITN(n)                                                  \
    do {                                                          \
        __builtin_amdgcn_sched_barrier(0);                        \
        asm volatile("s_waitcnt vmcnt(" #n ")" ::: "memory");     \
        __builtin_amdgcn_sched_barrier(0);                        \
    } while (0)

#define BAR() __builtin_amdgcn_s_barrier()

// ---- mega-prep: [0,1024) cvtX, [1024,3072) tw(W1), [3072,5120) zero out, 5120 routing,
// ----            [5121,7169) tw(W2)  (only dispatched in fused mode) ----
__global__ void k_prep(const float* __restrict__ X, unsigned short* __restrict__ Xb,
                       const float* __restrict__ W1, unsigned short* __restrict__ W1T,
                       const float* __restrict__ W2, unsigned short* __restrict__ W2T,
                       float* __restrict__ outz,
                       const int* __restrict__ sel, int* __restrict__ counts_g,
                       int* __restrict__ opad_g, int* __restrict__ rowmap,
                       float* __restrict__ loads_out) {
    __shared__ unsigned short T[64][65];
    __shared__ int hist[NE], cur[NE], off[NE];
    const int b = blockIdx.x, tid = threadIdx.x;

    if (b < 1024) {  // X fp32 -> bf16
        int i = (b * 256 + tid) * 8;
        float4 a = *(const float4*)(X + i);
        float4 c = *(const float4*)(X + i + 4);
        uint4 u;
        u.x = pack2(a.x, a.y); u.y = pack2(a.z, a.w);
        u.z = pack2(c.x, c.y); u.w = pack2(c.z, c.w);
        *(uint4*)(Xb + i) = u;
    } else if (b < 3072) {  // W1 [E][DM][DF] -> bf16 W1T [E][DF][DM]
        const int t = b - 1024;
        const int bx = t & 31, by = (t >> 5) & 7, bz = t >> 8;
        const int tx = tid & 15, ty = tid >> 4;
        const int r0 = by * 64, c0 = bx * 64;
        const float* src = W1 + ((size_t)bz * DM + r0) * DF + c0;
#pragma unroll
        for (int i = 0; i < 4; ++i) {
            int r = ty + i * 16;
            float4 v = *(const float4*)(src + (size_t)r * DF + tx * 4);
            T[tx * 4 + 0][r] = f2bf(v.x); T[tx * 4 + 1][r] = f2bf(v.y);
            T[tx * 4 + 2][r] = f2bf(v.z); T[tx * 4 + 3][r] = f2bf(v.w);
        }
        __syncthreads();
        unsigned short* dst = W1T + ((size_t)bz * DF + c0) * DM + r0;
#pragma unroll
        for (int i = 0; i < 4; ++i) {
            int c = ty + i * 16;
            ushort4 w;
            w.x = T[c][tx * 4 + 0]; w.y = T[c][tx * 4 + 1];
            w.z = T[c][tx * 4 + 2]; w.w = T[c][tx * 4 + 3];
            *(ushort4*)(dst + (size_t)c * DM + tx * 4) = w;
        }
    } else if (b < 5120) {  // zero expert_outputs (gemm2 atomics accumulate into it)
        size_t i = ((size_t)(b - 3072) * 256 + tid) * 8;
        float4 z = make_float4(0.f, 0.f, 0.f, 0.f);
        *(float4*)(outz + i) = z;
        *(float4*)(outz + i + 4) = z;
    } else if (b == 5120) {  // routing: histogram + padded scan + compact assign
        if (tid < NE) { hist[tid] = 0; cur[tid] = 0; }
        __syncthreads();
#pragma unroll
        for (int i = 0; i < NPAIR / 256; ++i)
            atomicAdd(&hist[sel[i * 256 + tid]], 1);
        __syncthreads();
        if (tid == 0) {
            int s = 0;
            for (int e = 0; e < NE; ++e) {
                off[e] = s;
                s += (hist[e] + 127) & ~127;
                counts_g[e] = hist[e];
                opad_g[e] = off[e];
                loads_out[e] = (float)hist[e] * (1.0f / (float)NTOK);
            }
        }
        __syncthreads();
#pragma unroll
        for (int i = 0; i < NPAIR / 256; ++i) {
            int p = i * 256 + tid;
            int e = sel[p];
            int pos = atomicAdd(&cur[e], 1);
            rowmap[off[e] + pos] = p;
        }
    } else {  // W2 [E][DF][DM] -> bf16 W2T [E][DM][DF] (fused mode only)
        const int t = b - 5121;
        const int bx = t & 7, by = (t >> 3) & 31, bz = t >> 8;
        const int tx = tid & 15, ty = tid >> 4;
        const int r0 = by * 64, c0 = bx * 64;
        const float* src = W2 + ((size_t)bz * DF + r0) * DM + c0;
#pragma unroll
        for (int i = 0; i < 4; ++i) {
            int r = ty + i * 16;
            float4 v = *(const float4*)(src + (size_t)r * DM + tx * 4);
            T[tx * 4 + 0][r] = f2bf(v.x); T[tx * 4 + 1][r] = f2bf(v.y);
            T[tx * 4 + 2][r] = f2bf(v.z); T[tx * 4 + 3][r] = f2bf(v.w);
        }
        __syncthreads();
        unsigned short* dst = W2T + ((size_t)bz * DM + c0) * DF + r0;
#pragma unroll
        for (int i = 0; i < 4; ++i) {
            int c = ty + i * 16;
            ushort4 w;
            w.x = T[c][tx * 4 + 0]; w.y = T[c][tx * 4 + 1];
            w.z = T[c][tx * 4 + 2]; w.w = T[c][tx * 4 + 3];
            *(ushort4*)(dst + (size_t)c * DF + tx * 4) = w;
        }
    }
}

// ---- W2 [E][DF][DM] -> bf16 W2T [E][DM][DF] (fallback when ws too small to fuse) ----
__global__ void k_tw2(const float* __restrict__ in, unsigned short* __restrict__ out) {
    __shared__ unsigned short T[64][65];
    const int tid = threadIdx.x;
    const int tx = tid & 15, ty = tid >> 4;
    const int r0 = blockIdx.y * 64, c0 = blockIdx.x * 64;
    const float* src = in + ((size_t)blockIdx.z * DF + r0) * DM + c0;
#pragma unroll
    for (int i = 0; i < 4; ++i) {
        int r = ty + i * 16;
        float4 v = *(const float4*)(src + (size_t)r * DM + tx * 4);
        T[tx * 4 + 0][r] = f2bf(v.x); T[tx * 4 + 1][r] = f2bf(v.y);
        T[tx * 4 + 2][r] = f2bf(v.z); T[tx * 4 + 3][r] = f2bf(v.w);
    }
    __syncthreads();
    unsigned short* dst = out + ((size_t)blockIdx.z * DM + c0) * DF + r0;
#pragma unroll
    for (int i = 0; i < 4; ++i) {
        int c = ty + i * 16;
        ushort4 w;
        w.x = T[c][tx * 4 + 0]; w.y = T[c][tx * 4 + 1];
        w.z = T[c][tx * 4 + 2]; w.w = T[c][tx * 4 + 3];
        *(ushort4*)(dst + (size_t)c * DF + tx * 4) = w;
    }
}

// ---------------- GEMM1: H = gelu(Xb[tok] @ W1), 128x128, BK=64, dbuf counted-vmcnt ----
__launch_bounds__(256, 2)
__global__ void k_gemm1d(const unsigned short* __restrict__ Xb,
                         const unsigned short* __restrict__ W1T,
                         const int* __restrict__ counts, const int* __restrict__ opad,
                         const int* __restrict__ rowmap, unsigned short* __restrict__ H) {
    const int e = blockIdx.z, mt = blockIdx.y, nt = blockIdx.x;
    const int grow = opad[e] + mt * 128;
    int valid = counts[e] - mt * 128;
    if (valid <= 0) return;
    if (valid > 128) valid = 128;

    __shared__ __align__(16) unsigned short As[2][128 * 64];
    __shared__ __align__(16) unsigned short Bs[2][128 * 64];
    __shared__ int toks[128];

    const int tid = threadIdx.x;
    if (tid < 128) {
        int i = (tid < valid) ? tid : 0;
        toks[tid] = rowmap[grow + i] >> 1;
    }
    __syncthreads();

    const int wave = tid >> 6, lane = tid & 63;
    const int wm = wave >> 1, wn = wave & 1;
    const int quad = lane >> 4, l15 = lane & 15;

    // DMA mapping: 8 lanes/row, rows 128B-contiguous; global chunk pre-swizzled so the
    // linear LDS write lands at slot64(row, chunk) (m173 both-sides-or-neither rule)
    const unsigned short* ga[4];
    const unsigned short* gb[4];
    unsigned short* la[4];
    unsigned short* lb[4];
#pragma unroll
    for (int j = 0; j < 4; ++j) {
        int row = wave * 32 + j * 8 + (lane >> 3);
        int ch = (lane & 7) ^ ((lane >> 3) & 7);
        ga[j] = Xb + (size_t)toks[row] * DM + ch * 8;
        gb[j] = W1T + ((size_t)e * DF + nt * 128 + row) * DM + ch * 8;
        la[j] = &As[0][(wave * 32 + j * 8) * 64];
        lb[j] = &Bs[0][(wave * 32 + j * 8) * 64];
    }

    f32x4 acc[4][4] = {};

    STAGE(0, 0);
#pragma unroll 1
    for (int kt = 0; kt < 8; kt += 2) {
        if (kt + 1 < 8) { STAGE(1, (kt + 1) * 64); WAITN(8); } else { WAITN(0); }
        BAR();
        mfma_step(&As[0][0], &Bs[0][0], wm, wn, quad, l15, acc);
        BAR();
        if (kt + 2 < 8) { STAGE(0, (kt + 2) * 64); WAITN(8); } else { WAITN(0); }
        BAR();
        mfma_step(&As[1][0], &Bs[1][0], wm, wn, quad, l15, acc);
        BAR();
    }

#pragma unroll
    for (int fm = 0; fm < 4; ++fm) {
#pragma unroll
        for (int i = 0; i < 4; ++i) {
            int m_l = wm * 64 + fm * 16 + quad * 4 + i;
            if (m_l < valid) {
                unsigned short* hrow = H + (size_t)(grow + m_l) * DF + nt * 128 + wn * 64;
#pragma unroll
                for (int fn = 0; fn < 4; ++fn)
                    hrow[fn * 16 + l15] = f2bf(gelu_fast(acc[fm][fn][i]));
            }
        }
    }
}

// ---------------- GEMM2: out += H @ W2, 128x128, BK=64, split-K x2, dbuf counted-vmcnt --
__launch_bounds__(256, 2)
__global__ void k_gemm2d(const unsigned short* __restrict__ H,
                         const unsigned short* __restrict__ W2T,
                         const int* __restrict__ counts, const int* __restrict__ opad,
                         const int* __restrict__ rowmap, float* __restrict__ out) {
    const int e = blockIdx.z, mt = blockIdx.y;
    const int nt = blockIdx.x & 3, ks = blockIdx.x >> 2;  // ks in {0,1}, K=1024 each
    const int grow = opad[e] + mt * 128;
    int valid = counts[e] - mt * 128;
    if (valid <= 0) return;
    if (valid > 128) valid = 128;

    __shared__ __align__(16) unsigned short As[2][128 * 64];
    __shared__ __align__(16) unsigned short Bs[2][128 * 64];
    __shared__ int pairs[128];

    const int tid = threadIdx.x;
    if (tid < 128) pairs[tid] = (tid < valid) ? rowmap[grow + tid] : 0;
    __syncthreads();

    const int wave = tid >> 6, lane = tid & 63;
    const int wm = wave >> 1, wn = wave & 1;
    const int quad = lane >> 4, l15 = lane & 15;

    const unsigned short* ga[4];
    const unsigned short* gb[4];
    unsigned short* la[4];
    unsigned short* lb[4];
#pragma unroll
    for (int j = 0; j < 4; ++j) {
        int row = wave * 32 + j * 8 + (lane >> 3);
        int ch = (lane & 7) ^ ((lane >> 3) & 7);
        int rr = (row < valid) ? row : 0;  // clamp: never read unwritten H (r7 lesson)
        ga[j] = H + (size_t)(grow + rr) * DF + ks * 1024 + ch * 8;
        gb[j] = W2T + ((size_t)e * DM + nt * 128 + row) * DF + ks * 1024 + ch * 8;
        la[j] = &As[0][(wave * 32 + j * 8) * 64];
        lb[j] = &Bs[0][(wave * 32 + j * 8) * 64];
    }

    f32x4 acc[4][4] = {};

    STAGE(0, 0);
#pragma unroll 1
    for (int kt = 0; kt < 16; kt += 2) {
        if (kt + 1 < 16) { STAGE(1, (kt + 1) * 64); WAITN(8); } else { WAITN(0); }
        BAR();
        mfma_step(&As[0][0], &Bs[0][0], wm, wn, quad, l15, acc);
        BAR();
        if (kt + 2 < 16) { STAGE(0, (kt + 2) * 64); WAITN(8); } else { WAITN(0); }
        BAR();
        mfma_step(&As[1][0], &Bs[1][0], wm, wn, quad, l15, acc);
        BAR();
    }

#pragma unroll
    for (int fm = 0; fm < 4; ++fm) {
#pragma unroll
        for (int i = 0; i < 4; ++i) {
            int m_l = wm * 64 + fm * 16 + quad * 4 + i;
            if (m_l < valid) {
                float* orow = out + (size_t)pairs[m_l] * DM + nt * 128 + wn * 64;
#pragma unroll
                for (int fn = 0; fn < 4; ++fn)
                    atomicAdd(&orow[fn * 16 + l15], acc[fm][fn][i]);
            }
        }
    }
}

extern "C" void kernel_launch(void* const* d_in, const int* in_sizes, int n_in,
                              void* d_out, int out_size, void* d_ws, size_t ws_size,
                              hipStream_t stream) {
    const float* X = (const float*)d_in[0];
    const int* sel = (const int*)d_in[1];
    const float* W1 = (const float*)d_in[3];
    const float* W2 = (const float*)d_in[4];
    float* out = (float*)d_out;
    float* loads_out = out + (size_t)NPAIR * DM;

    int* counts = (int*)d_ws;
    int* opad = counts + 16;
    int* rowmap = counts + 32;
    const size_t hbytes = (size_t)HCAP * DF * 2;
    const size_t xbytes = (size_t)NTOK * DM * 2;
    const size_t w1tbytes = (size_t)NE * DF * DM * 2;
    unsigned short* H = (unsigned short*)((char*)d_ws + 65536);
    unsigned short* Xb = (unsigned short*)((char*)d_ws + 65536 + hbytes);
    unsigned short* WT = (unsigned short*)((char*)d_ws + 65536 + hbytes + xbytes);

    // fused mode: separate W2T buffer -> W2 transpose folds into k_prep, no k_tw2 dispatch
    const bool fused = ws_size >= 65536 + hbytes + xbytes + 2 * w1tbytes;
    unsigned short* W2T = fused ? WT + w1tbytes / 2 : WT;

    hipLaunchKernelGGL(k_prep, dim3(fused ? 7169 : 5121), dim3(256), 0, stream,
                       X, Xb, W1, WT, W2, W2T, out, sel, counts, opad, rowmap, loads_out);
    hipLaunchKernelGGL(k_gemm1d, dim3(DF / 128, NPAIR / 128, NE), dim3(256), 0, stream,
                       Xb, WT, counts, opad, rowmap, H);
    if (!fused)
        hipLaunchKernelGGL(k_tw2, dim3(DM / 64, DF / 64, NE), dim3(256), 0, stream, W2, WT);
    hipLaunchKernelGGL(k_gemm2d, dim3(8, NPAIR / 128, NE), dim3(256), 0, stream,
                       H, W2T, counts, opad, rowmap, out);
}

// Round 4
// 202.464 us; speedup vs baseline: 1.2420x; 1.1038x over previous
//
#include <hip/hip_runtime.h>
#include <hip/hip_bf16.h>

// ExpertBank MoE FFN on gfx950 — round 13.
// r12 post-mortem: BK=64 worked (WRITE=32MB exactly as predicted, 80->58us), but r9-vs-r12
// linear fit shows f32-atomic RMW serialization ~2.4us/M-atomic => ~20us of gemm2's 58us.
// Fix: drop split-K entirely (256 working blocks = 1/CU, still chip-filling), out written
// exactly once -> PLAIN STORES, zero atomics, and the out-zeroing prep phase (2048 blocks,
// 16.7MB writes) is deleted. K-loop 32 steps, same BK=64 dbuf counted-vmcnt(8) pipeline.
// ws: int[0..7] counts, [16..23] opad, [32..) rowmap(9216),
//     byte 65536: H bf16 [9216][2048] (37.75 MB), Xb bf16 (4.2 MB),
//     W1T bf16 (16.8 MB), [optional] W2T bf16 (16.8 MB).

typedef __bf16 bf16x8 __attribute__((ext_vector_type(8)));
typedef float f32x4 __attribute__((ext_vector_type(4)));

#define DM 512
#define DF 2048
#define NE 8
#define NTOK 4096
#define NPAIR 8192
#define HCAP 9216

__device__ __forceinline__ unsigned short f2bf(float x) {
    unsigned u = __builtin_bit_cast(unsigned, x);
    return (unsigned short)((u + 0x7fffu + ((u >> 16) & 1u)) >> 16);
}
__device__ __forceinline__ unsigned pack2(float lo, float hi) {
    return (unsigned)f2bf(lo) | ((unsigned)f2bf(hi) << 16);
}
__device__ __forceinline__ float gelu_fast(float x) {
    // tanh-form GELU via exp: |err| <= ~3e-4 absolute, negligible vs bf16 path
    float y = 0.7978845608028654f * (x + 0.044715f * x * x * x);
    float e = __expf(2.0f * y);
    float t = 1.0f - 2.0f / (e + 1.0f);
    return 0.5f * x * (1.0f + t);
}
// async 16B global->LDS (gfx950); lds pointer must be wave-uniform, writes lane*16B
__device__ __forceinline__ void dma16(const unsigned short* g, unsigned short* l) {
    __builtin_amdgcn_global_load_lds(
        (const __attribute__((address_space(1))) void*)g,
        (__attribute__((address_space(3))) void*)l, 16, 0, 0);
}
// BK=64 tile [128][64] bf16: 8 16B-chunks per 128B row; XOR swizzle chunk^(row&7).
// Read side: lanes 0..15 hit 8 distinct chunk slots x2 rows = 2-way bank alias = free.
__device__ __forceinline__ int slot64(int row, int c) { return row * 8 + (c ^ (row & 7)); }

// one 128x128x64 MFMA step (2 x K=32 sub-steps) from swizzled LDS tiles
__device__ __forceinline__ void mfma_step(const unsigned short* Ab, const unsigned short* Bb,
                                          int wm, int wn, int quad, int l15,
                                          f32x4 (&acc)[4][4]) {
#pragma unroll
    for (int kk = 0; kk < 2; ++kk) {
        const int c = kk * 4 + quad;
        bf16x8 a[4], b[4];
#pragma unroll
        for (int fm = 0; fm < 4; ++fm) {
            int row = wm * 64 + fm * 16 + l15;
            a[fm] = __builtin_bit_cast(bf16x8, *(const uint4*)&Ab[slot64(row, c) * 8]);
        }
#pragma unroll
        for (int fn = 0; fn < 4; ++fn) {
            int row = wn * 64 + fn * 16 + l15;
            b[fn] = __builtin_bit_cast(bf16x8, *(const uint4*)&Bb[slot64(row, c) * 8]);
        }
#pragma unroll
        for (int fm = 0; fm < 4; ++fm)
#pragma unroll
            for (int fn = 0; fn < 4; ++fn)
                acc[fm][fn] = __builtin_amdgcn_mfma_f32_16x16x32_bf16(a[fm], b[fn], acc[fm][fn], 0, 0, 0);
    }
}

// 8 dma16 per wave per STAGE (4 A + 4 B); ko in ushort elements; buf stride 8192 ushorts
#define STAGE(buf, ko)                                        \
    do {                                                      \
        _Pragma("unroll") for (int j_ = 0; j_ < 4; ++j_) {    \
            dma16(ga[j_] + (ko), la[j_] + (buf) * 8192);      \
            dma16(gb[j_] + (ko), lb[j_] + (buf) * 8192);      \
        }                                                     \
    } while (0)

#define WAITN(n)                                                  \
    do {                                                          \
        __builtin_amdgcn_sched_barrier(0);                        \
        asm volatile("s_waitcnt vmcnt(" #n ")" ::: "memory");     \
        __builtin_amdgcn_sched_barrier(0);                        \
    } while (0)

#define BAR() __builtin_amdgcn_s_barrier()

// ---- mega-prep: [0,1024) cvtX, [1024,3072) tw(W1), 3072 routing,
// ----            [3073,5121) tw(W2)  (only dispatched in fused mode) ----
__global__ void k_prep(const float* __restrict__ X, unsigned short* __restrict__ Xb,
                       const float* __restrict__ W1, unsigned short* __restrict__ W1T,
                       const float* __restrict__ W2, unsigned short* __restrict__ W2T,
                       const int* __restrict__ sel, int* __restrict__ counts_g,
                       int* __restrict__ opad_g, int* __restrict__ rowmap,
                       float* __restrict__ loads_out) {
    __shared__ unsigned short T[64][65];
    __shared__ int hist[NE], cur[NE], off[NE];
    const int b = blockIdx.x, tid = threadIdx.x;

    if (b < 1024) {  // X fp32 -> bf16
        int i = (b * 256 + tid) * 8;
        float4 a = *(const float4*)(X + i);
        float4 c = *(const float4*)(X + i + 4);
        uint4 u;
        u.x = pack2(a.x, a.y); u.y = pack2(a.z, a.w);
        u.z = pack2(c.x, c.y); u.w = pack2(c.z, c.w);
        *(uint4*)(Xb + i) = u;
    } else if (b < 3072) {  // W1 [E][DM][DF] -> bf16 W1T [E][DF][DM]
        const int t = b - 1024;
        const int bx = t & 31, by = (t >> 5) & 7, bz = t >> 8;
        const int tx = tid & 15, ty = tid >> 4;
        const int r0 = by * 64, c0 = bx * 64;
        const float* src = W1 + ((size_t)bz * DM + r0) * DF + c0;
#pragma unroll
        for (int i = 0; i < 4; ++i) {
            int r = ty + i * 16;
            float4 v = *(const float4*)(src + (size_t)r * DF + tx * 4);
            T[tx * 4 + 0][r] = f2bf(v.x); T[tx * 4 + 1][r] = f2bf(v.y);
            T[tx * 4 + 2][r] = f2bf(v.z); T[tx * 4 + 3][r] = f2bf(v.w);
        }
        __syncthreads();
        unsigned short* dst = W1T + ((size_t)bz * DF + c0) * DM + r0;
#pragma unroll
        for (int i = 0; i < 4; ++i) {
            int c = ty + i * 16;
            ushort4 w;
            w.x = T[c][tx * 4 + 0]; w.y = T[c][tx * 4 + 1];
            w.z = T[c][tx * 4 + 2]; w.w = T[c][tx * 4 + 3];
            *(ushort4*)(dst + (size_t)c * DM + tx * 4) = w;
        }
    } else if (b == 3072) {  // routing: histogram + padded scan + compact assign
        if (tid < NE) { hist[tid] = 0; cur[tid] = 0; }
        __syncthreads();
#pragma unroll
        for (int i = 0; i < NPAIR / 256; ++i)
            atomicAdd(&hist[sel[i * 256 + tid]], 1);
        __syncthreads();
        if (tid == 0) {
            int s = 0;
            for (int e = 0; e < NE; ++e) {
                off[e] = s;
                s += (hist[e] + 127) & ~127;
                counts_g[e] = hist[e];
                opad_g[e] = off[e];
                loads_out[e] = (float)hist[e] * (1.0f / (float)NTOK);
            }
        }
        __syncthreads();
#pragma unroll
        for (int i = 0; i < NPAIR / 256; ++i) {
            int p = i * 256 + tid;
            int e = sel[p];
            int pos = atomicAdd(&cur[e], 1);
            rowmap[off[e] + pos] = p;
        }
    } else {  // W2 [E][DF][DM] -> bf16 W2T [E][DM][DF] (fused mode only)
        const int t = b - 3073;
        const int bx = t & 7, by = (t >> 3) & 31, bz = t >> 8;
        const int tx = tid & 15, ty = tid >> 4;
        const int r0 = by * 64, c0 = bx * 64;
        const float* src = W2 + ((size_t)bz * DF + r0) * DM + c0;
#pragma unroll
        for (int i = 0; i < 4; ++i) {
            int r = ty + i * 16;
            float4 v = *(const float4*)(src + (size_t)r * DM + tx * 4);
            T[tx * 4 + 0][r] = f2bf(v.x); T[tx * 4 + 1][r] = f2bf(v.y);
            T[tx * 4 + 2][r] = f2bf(v.z); T[tx * 4 + 3][r] = f2bf(v.w);
        }
        __syncthreads();
        unsigned short* dst = W2T + ((size_t)bz * DM + c0) * DF + r0;
#pragma unroll
        for (int i = 0; i < 4; ++i) {
            int c = ty + i * 16;
            ushort4 w;
            w.x = T[c][tx * 4 + 0]; w.y = T[c][tx * 4 + 1];
            w.z = T[c][tx * 4 + 2]; w.w = T[c][tx * 4 + 3];
            *(ushort4*)(dst + (size_t)c * DF + tx * 4) = w;
        }
    }
}

// ---- W2 [E][DF][DM] -> bf16 W2T [E][DM][DF] (fallback when ws too small to fuse) ----
__global__ void k_tw2(const float* __restrict__ in, unsigned short* __restrict__ out) {
    __shared__ unsigned short T[64][65];
    const int tid = threadIdx.x;
    const int tx = tid & 15, ty = tid >> 4;
    const int r0 = blockIdx.y * 64, c0 = blockIdx.x * 64;
    const float* src = in + ((size_t)blockIdx.z * DF + r0) * DM + c0;
#pragma unroll
    for (int i = 0; i < 4; ++i) {
        int r = ty + i * 16;
        float4 v = *(const float4*)(src + (size_t)r * DM + tx * 4);
        T[tx * 4 + 0][r] = f2bf(v.x); T[tx * 4 + 1][r] = f2bf(v.y);
        T[tx * 4 + 2][r] = f2bf(v.z); T[tx * 4 + 3][r] = f2bf(v.w);
    }
    __syncthreads();
    unsigned short* dst = out + ((size_t)blockIdx.z * DM + c0) * DF + r0;
#pragma unroll
    for (int i = 0; i < 4; ++i) {
        int c = ty + i * 16;
        ushort4 w;
        w.x = T[c][tx * 4 + 0]; w.y = T[c][tx * 4 + 1];
        w.z = T[c][tx * 4 + 2]; w.w = T[c][tx * 4 + 3];
        *(ushort4*)(dst + (size_t)c * DF + tx * 4) = w;
    }
}

// ---------------- GEMM1: H = gelu(Xb[tok] @ W1), 128x128, BK=64, dbuf counted-vmcnt ----
__launch_bounds__(256, 2)
__global__ void k_gemm1d(const unsigned short* __restrict__ Xb,
                         const unsigned short* __restrict__ W1T,
                         const int* __restrict__ counts, const int* __restrict__ opad,
                         const int* __restrict__ rowmap, unsigned short* __restrict__ H) {
    const int e = blockIdx.z, mt = blockIdx.y, nt = blockIdx.x;
    const int grow = opad[e] + mt * 128;
    int valid = counts[e] - mt * 128;
    if (valid <= 0) return;
    if (valid > 128) valid = 128;

    __shared__ __align__(16) unsigned short As[2][128 * 64];
    __shared__ __align__(16) unsigned short Bs[2][128 * 64];
    __shared__ int toks[128];

    const int tid = threadIdx.x;
    if (tid < 128) {
        int i = (tid < valid) ? tid : 0;
        toks[tid] = rowmap[grow + i] >> 1;
    }
    __syncthreads();

    const int wave = tid >> 6, lane = tid & 63;
    const int wm = wave >> 1, wn = wave & 1;
    const int quad = lane >> 4, l15 = lane & 15;

    // DMA mapping: 8 lanes/row, rows 128B-contiguous; global chunk pre-swizzled so the
    // linear LDS write lands at slot64(row, chunk) (m173 both-sides-or-neither rule)
    const unsigned short* ga[4];
    const unsigned short* gb[4];
    unsigned short* la[4];
    unsigned short* lb[4];
#pragma unroll
    for (int j = 0; j < 4; ++j) {
        int row = wave * 32 + j * 8 + (lane >> 3);
        int ch = (lane & 7) ^ ((lane >> 3) & 7);
        ga[j] = Xb + (size_t)toks[row] * DM + ch * 8;
        gb[j] = W1T + ((size_t)e * DF + nt * 128 + row) * DM + ch * 8;
        la[j] = &As[0][(wave * 32 + j * 8) * 64];
        lb[j] = &Bs[0][(wave * 32 + j * 8) * 64];
    }

    f32x4 acc[4][4] = {};

    STAGE(0, 0);
#pragma unroll 1
    for (int kt = 0; kt < 8; kt += 2) {
        if (kt + 1 < 8) { STAGE(1, (kt + 1) * 64); WAITN(8); } else { WAITN(0); }
        BAR();
        mfma_step(&As[0][0], &Bs[0][0], wm, wn, quad, l15, acc);
        BAR();
        if (kt + 2 < 8) { STAGE(0, (kt + 2) * 64); WAITN(8); } else { WAITN(0); }
        BAR();
        mfma_step(&As[1][0], &Bs[1][0], wm, wn, quad, l15, acc);
        BAR();
    }

#pragma unroll
    for (int fm = 0; fm < 4; ++fm) {
#pragma unroll
        for (int i = 0; i < 4; ++i) {
            int m_l = wm * 64 + fm * 16 + quad * 4 + i;
            if (m_l < valid) {
                unsigned short* hrow = H + (size_t)(grow + m_l) * DF + nt * 128 + wn * 64;
#pragma unroll
                for (int fn = 0; fn < 4; ++fn)
                    hrow[fn * 16 + l15] = f2bf(gelu_fast(acc[fm][fn][i]));
            }
        }
    }
}

// ------- GEMM2: out = H @ W2 (K=2048, no split-K, plain stores), BK=64 dbuf ----------
__launch_bounds__(256, 2)
__global__ void k_gemm2d(const unsigned short* __restrict__ H,
                         const unsigned short* __restrict__ W2T,
                         const int* __restrict__ counts, const int* __restrict__ opad,
                         const int* __restrict__ rowmap, float* __restrict__ out) {
    const int e = blockIdx.z, mt = blockIdx.y, nt = blockIdx.x;
    const int grow = opad[e] + mt * 128;
    int valid = counts[e] - mt * 128;
    if (valid <= 0) return;
    if (valid > 128) valid = 128;

    __shared__ __align__(16) unsigned short As[2][128 * 64];
    __shared__ __align__(16) unsigned short Bs[2][128 * 64];
    __shared__ int pairs[128];

    const int tid = threadIdx.x;
    if (tid < 128) pairs[tid] = (tid < valid) ? rowmap[grow + tid] : 0;
    __syncthreads();

    const int wave = tid >> 6, lane = tid & 63;
    const int wm = wave >> 1, wn = wave & 1;
    const int quad = lane >> 4, l15 = lane & 15;

    const unsigned short* ga[4];
    const unsigned short* gb[4];
    unsigned short* la[4];
    unsigned short* lb[4];
#pragma unroll
    for (int j = 0; j < 4; ++j) {
        int row = wave * 32 + j * 8 + (lane >> 3);
        int ch = (lane & 7) ^ ((lane >> 3) & 7);
        int rr = (row < valid) ? row : 0;  // clamp: never read unwritten H (r7 lesson)
        ga[j] = H + (size_t)(grow + rr) * DF + ch * 8;
        gb[j] = W2T + ((size_t)e * DM + nt * 128 + row) * DF + ch * 8;
        la[j] = &As[0][(wave * 32 + j * 8) * 64];
        lb[j] = &Bs[0][(wave * 32 + j * 8) * 64];
    }

    f32x4 acc[4][4] = {};

    STAGE(0, 0);
#pragma unroll 1
    for (int kt = 0; kt < 32; kt += 2) {
        if (kt + 1 < 32) { STAGE(1, (kt + 1) * 64); WAITN(8); } else { WAITN(0); }
        BAR();
        mfma_step(&As[0][0], &Bs[0][0], wm, wn, quad, l15, acc);
        BAR();
        if (kt + 2 < 32) { STAGE(0, (kt + 2) * 64); WAITN(8); } else { WAITN(0); }
        BAR();
        mfma_step(&As[1][0], &Bs[1][0], wm, wn, quad, l15, acc);
        BAR();
    }

#pragma unroll
    for (int fm = 0; fm < 4; ++fm) {
#pragma unroll
        for (int i = 0; i < 4; ++i) {
            int m_l = wm * 64 + fm * 16 + quad * 4 + i;
            if (m_l < valid) {
                float* orow = out + (size_t)pairs[m_l] * DM + nt * 128 + wn * 64;
#pragma unroll
                for (int fn = 0; fn < 4; ++fn)
                    orow[fn * 16 + l15] = acc[fm][fn][i];  // exactly-once: plain store
            }
        }
    }
}

extern "C" void kernel_launch(void* const* d_in, const int* in_sizes, int n_in,
                              void* d_out, int out_size, void* d_ws, size_t ws_size,
                              hipStream_t stream) {
    const float* X = (const float*)d_in[0];
    const int* sel = (const int*)d_in[1];
    const float* W1 = (const float*)d_in[3];
    const float* W2 = (const float*)d_in[4];
    float* out = (float*)d_out;
    float* loads_out = out + (size_t)NPAIR * DM;

    int* counts = (int*)d_ws;
    int* opad = counts + 16;
    int* rowmap = counts + 32;
    const size_t hbytes = (size_t)HCAP * DF * 2;
    const size_t xbytes = (size_t)NTOK * DM * 2;
    const size_t w1tbytes = (size_t)NE * DF * DM * 2;
    unsigned short* H = (unsigned short*)((char*)d_ws + 65536);
    unsigned short* Xb = (unsigned short*)((char*)d_ws + 65536 + hbytes);
    unsigned short* WT = (unsigned short*)((char*)d_ws + 65536 + hbytes + xbytes);

    // fused mode: separate W2T buffer -> W2 transpose folds into k_prep, no k_tw2 dispatch
    const bool fused = ws_size >= 65536 + hbytes + xbytes + 2 * w1tbytes;
    unsigned short* W2T = fused ? WT + w1tbytes / 2 : WT;

    hipLaunchKernelGGL(k_prep, dim3(fused ? 5121 : 3073), dim3(256), 0, stream,
                       X, Xb, W1, WT, W2, W2T, sel, counts, opad, rowmap, loads_out);
    hipLaunchKernelGGL(k_gemm1d, dim3(DF / 128, NPAIR / 128, NE), dim3(256), 0, stream,
                       Xb, WT, counts, opad, rowmap, H);
    if (!fused)
        hipLaunchKernelGGL(k_tw2, dim3(DM / 64, DF / 64, NE), dim3(256), 0, stream, W2, WT);
    hipLaunchKernelGGL(k_gemm2d, dim3(4, NPAIR / 128, NE), dim3(256), 0, stream,
                       H, W2T, counts, opad, rowmap, out);
}

// Round 5
// 195.646 us; speedup vs baseline: 1.2853x; 1.0348x over previous
//
#include <hip/hip_runtime.h>
#include <hip/hip_bf16.h>

// ExpertBank MoE FFN on gfx950 — round 14.
// r13 post-mortem: atomics removal confirmed (gemm2 off top-5). New leader k_gemm1d 66us,
// VALUBusy 23% (2x gemm2): epilogue-bound — 64x(gelu+manual f2bf) VALU + 64 scalar 2B
// global stores/thread => ~1.2M scattered 32B write segments (same request-rate poison
// r11 fixed on the load side). Fix (k_gemm1d only): (1) epilogue through LDS — C-tile
// bf16 into dead staging LDS (stride 136), then 8 coalesced dwordx4 stores/thread;
// (2) gelu rewritten x*rcp(1+exp2(z)) with log2e folded: 5 VALU + 2 trans, same formula
// (err ~3e-4), f2bf RNE untouched. Pad rows stored unconditionally (gemm2 clamp covers).
// ws: int[0..7] counts, [16..23] opad, [32..) rowmap(9216),
//     byte 65536: H bf16 [9216][2048] (37.75 MB), Xb bf16 (4.2 MB),
//     W1T bf16 (16.8 MB), [optional] W2T bf16 (16.8 MB).

typedef __bf16 bf16x8 __attribute__((ext_vector_type(8)));
typedef float f32x4 __attribute__((ext_vector_type(4)));

#define DM 512
#define DF 2048
#define NE 8
#define NTOK 4096
#define NPAIR 8192
#define HCAP 9216

__device__ __forceinline__ unsigned short f2bf(float x) {
    unsigned u = __builtin_bit_cast(unsigned, x);
    return (unsigned short)((u + 0x7fffu + ((u >> 16) & 1u)) >> 16);
}
__device__ __forceinline__ unsigned pack2(float lo, float hi) {
    return (unsigned)f2bf(lo) | ((unsigned)f2bf(hi) << 16);
}
// tanh-form GELU == x*sigmoid(2y), y=0.79788456*(x+0.044715x^3); log2e folded:
// z = x*(c1 + c2*x^2), gelu = x * rcp(1 + exp2(z)). |err| ~3e-4 (same formula as r9-r13).
__device__ __forceinline__ float gelu_fast(float x) {
    float x2 = x * x;
    float z = x * __builtin_fmaf(x2, -0.1029432f, -2.3022083f);
    float e = __builtin_amdgcn_exp2f(z);
    return x * __builtin_amdgcn_rcpf(1.0f + e);
}
// async 16B global->LDS (gfx950); lds pointer must be wave-uniform, writes lane*16B
__device__ __forceinline__ void dma16(const unsigned short* g, unsigned short* l) {
    __builtin_amdgcn_global_load_lds(
        (const __attribute__((address_space(1))) void*)g,
        (__attribute__((address_space(3))) void*)l, 16, 0, 0);
}
// BK=64 tile [128][64] bf16: 8 16B-chunks per 128B row; XOR swizzle chunk^(row&7).
// Read side: lanes 0..15 hit 8 distinct chunk slots x2 rows = 2-way bank alias = free.
__device__ __forceinline__ int slot64(int row, int c) { return row * 8 + (c ^ (row & 7)); }

// one 128x128x64 MFMA step (2 x K=32 sub-steps) from swizzled LDS tiles
__device__ __forceinline__ void mfma_step(const unsigned short* Ab, const unsigned short* Bb,
                                          int wm, int wn, int quad, int l15,
                                          f32x4 (&acc)[4][4]) {
#pragma unroll
    for (int kk = 0; kk < 2; ++kk) {
        const int c = kk * 4 + quad;
        bf16x8 a[4], b[4];
#pragma unroll
        for (int fm = 0; fm < 4; ++fm) {
            int row = wm * 64 + fm * 16 + l15;
            a[fm] = __builtin_bit_cast(bf16x8, *(const uint4*)&Ab[slot64(row, c) * 8]);
        }
#pragma unroll
        for (int fn = 0; fn < 4; ++fn) {
            int row = wn * 64 + fn * 16 + l15;
            b[fn] = __builtin_bit_cast(bf16x8, *(const uint4*)&Bb[slot64(row, c) * 8]);
        }
#pragma unroll
        for (int fm = 0; fm < 4; ++fm)
#pragma unroll
            for (int fn = 0; fn < 4; ++fn)
                acc[fm][fn] = __builtin_amdgcn_mfma_f32_16x16x32_bf16(a[fm], b[fn], acc[fm][fn], 0, 0, 0);
    }
}

// 8 dma16 per wave per STAGE (4 A + 4 B); ko in ushort elements; buf stride 8192 ushorts
#define STAGE(buf, ko)                                        \
    do {                                                      \
        _Pragma("unroll") for (int j_ = 0; j_ < 4; ++j_) {    \
            dma16(ga[j_] + (ko), la[j_] + (buf) * 8192);      \
            dma16(gb[j_] + (ko), lb[j_] + (buf) * 8192);      \
        }                                                     \
    } while (0)

#define WAITN(n)                                                  \
    do {                                                          \
        __builtin_amdgcn_sched_barrier(0);                        \
        asm volatile("s_waitcnt vmcnt(" #n ")" ::: "memory");     \
        __builtin_amdgcn_sched_barrier(0);                        \
    } while (0)

#define BAR() __builtin_amdgcn_s_barrier()

// ---- mega-prep: [0,1024) cvtX, [1024,3072) tw(W1), 3072 routing,
// ----            [3073,5121) tw(W2)  (only dispatched in fused mode) ----
__global__ void k_prep(const float* __restrict__ X, unsigned short* __restrict__ Xb,
                       const float* __restrict__ W1, unsigned short* __restrict__ W1T,
                       const float* __restrict__ W2, unsigned short* __restrict__ W2T,
                       const int* __restrict__ sel, int* __restrict__ counts_g,
                       int* __restrict__ opad_g, int* __restrict__ rowmap,
                       float* __restrict__ loads_out) {
    __shared__ unsigned short T[64][65];
    __shared__ int hist[NE], cur[NE], off[NE];
    const int b = blockIdx.x, tid = threadIdx.x;

    if (b < 1024) {  // X fp32 -> bf16
        int i = (b * 256 + tid) * 8;
        float4 a = *(const float4*)(X + i);
        float4 c = *(const float4*)(X + i + 4);
        uint4 u;
        u.x = pack2(a.x, a.y); u.y = pack2(a.z, a.w);
        u.z = pack2(c.x, c.y); u.w = pack2(c.z, c.w);
        *(uint4*)(Xb + i) = u;
    } else if (b < 3072) {  // W1 [E][DM][DF] -> bf16 W1T [E][DF][DM]
        const int t = b - 1024;
        const int bx = t & 31, by = (t >> 5) & 7, bz = t >> 8;
        const int tx = tid & 15, ty = tid >> 4;
        const int r0 = by * 64, c0 = bx * 64;
        const float* src = W1 + ((size_t)bz * DM + r0) * DF + c0;
#pragma unroll
        for (int i = 0; i < 4; ++i) {
            int r = ty + i * 16;
            float4 v = *(const float4*)(src + (size_t)r * DF + tx * 4);
            T[tx * 4 + 0][r] = f2bf(v.x); T[tx * 4 + 1][r] = f2bf(v.y);
            T[tx * 4 + 2][r] = f2bf(v.z); T[tx * 4 + 3][r] = f2bf(v.w);
        }
        __syncthreads();
        unsigned short* dst = W1T + ((size_t)bz * DF + c0) * DM + r0;
#pragma unroll
        for (int i = 0; i < 4; ++i) {
            int c = ty + i * 16;
            ushort4 w;
            w.x = T[c][tx * 4 + 0]; w.y = T[c][tx * 4 + 1];
            w.z = T[c][tx * 4 + 2]; w.w = T[c][tx * 4 + 3];
            *(ushort4*)(dst + (size_t)c * DM + tx * 4) = w;
        }
    } else if (b == 3072) {  // routing: histogram + padded scan + compact assign
        if (tid < NE) { hist[tid] = 0; cur[tid] = 0; }
        __syncthreads();
#pragma unroll
        for (int i = 0; i < NPAIR / 256; ++i)
            atomicAdd(&hist[sel[i * 256 + tid]], 1);
        __syncthreads();
        if (tid == 0) {
            int s = 0;
            for (int e = 0; e < NE; ++e) {
                off[e] = s;
                s += (hist[e] + 127) & ~127;
                counts_g[e] = hist[e];
                opad_g[e] = off[e];
                loads_out[e] = (float)hist[e] * (1.0f / (float)NTOK);
            }
        }
        __syncthreads();
#pragma unroll
        for (int i = 0; i < NPAIR / 256; ++i) {
            int p = i * 256 + tid;
            int e = sel[p];
            int pos = atomicAdd(&cur[e], 1);
            rowmap[off[e] + pos] = p;
        }
    } else {  // W2 [E][DF][DM] -> bf16 W2T [E][DM][DF] (fused mode only)
        const int t = b - 3073;
        const int bx = t & 7, by = (t >> 3) & 31, bz = t >> 8;
        const int tx = tid & 15, ty = tid >> 4;
        const int r0 = by * 64, c0 = bx * 64;
        const float* src = W2 + ((size_t)bz * DF + r0) * DM + c0;
#pragma unroll
        for (int i = 0; i < 4; ++i) {
            int r = ty + i * 16;
            float4 v = *(const float4*)(src + (size_t)r * DM + tx * 4);
            T[tx * 4 + 0][r] = f2bf(v.x); T[tx * 4 + 1][r] = f2bf(v.y);
            T[tx * 4 + 2][r] = f2bf(v.z); T[tx * 4 + 3][r] = f2bf(v.w);
        }
        __syncthreads();
        unsigned short* dst = W2T + ((size_t)bz * DM + c0) * DF + r0;
#pragma unroll
        for (int i = 0; i < 4; ++i) {
            int c = ty + i * 16;
            ushort4 w;
            w.x = T[c][tx * 4 + 0]; w.y = T[c][tx * 4 + 1];
            w.z = T[c][tx * 4 + 2]; w.w = T[c][tx * 4 + 3];
            *(ushort4*)(dst + (size_t)c * DF + tx * 4) = w;
        }
    }
}

// ---- W2 [E][DF][DM] -> bf16 W2T [E][DM][DF] (fallback when ws too small to fuse) ----
__global__ void k_tw2(const float* __restrict__ in, unsigned short* __restrict__ out) {
    __shared__ unsigned short T[64][65];
    const int tid = threadIdx.x;
    const int tx = tid & 15, ty = tid >> 4;
    const int r0 = blockIdx.y * 64, c0 = blockIdx.x * 64;
    const float* src = in + ((size_t)blockIdx.z * DF + r0) * DM + c0;
#pragma unroll
    for (int i = 0; i < 4; ++i) {
        int r = ty + i * 16;
        float4 v = *(const float4*)(src + (size_t)r * DM + tx * 4);
        T[tx * 4 + 0][r] = f2bf(v.x); T[tx * 4 + 1][r] = f2bf(v.y);
        T[tx * 4 + 2][r] = f2bf(v.z); T[tx * 4 + 3][r] = f2bf(v.w);
    }
    __syncthreads();
    unsigned short* dst = out + ((size_t)blockIdx.z * DM + c0) * DF + r0;
#pragma unroll
    for (int i = 0; i < 4; ++i) {
        int c = ty + i * 16;
        ushort4 w;
        w.x = T[c][tx * 4 + 0]; w.y = T[c][tx * 4 + 1];
        w.z = T[c][tx * 4 + 2]; w.w = T[c][tx * 4 + 3];
        *(ushort4*)(dst + (size_t)c * DF + tx * 4) = w;
    }
}

// ---------------- GEMM1: H = gelu(Xb[tok] @ W1), 128x128, BK=64, dbuf counted-vmcnt ----
// LDS: SM[0..1] = A dbuf, SM[2..3] = B dbuf; epilogue reuses SM as [128][136] bf16 C-tile.
__launch_bounds__(256, 2)
__global__ void k_gemm1d(const unsigned short* __restrict__ Xb,
                         const unsigned short* __restrict__ W1T,
                         const int* __restrict__ counts, const int* __restrict__ opad,
                         const int* __restrict__ rowmap, unsigned short* __restrict__ H) {
    const int e = blockIdx.z, mt = blockIdx.y, nt = blockIdx.x;
    const int grow = opad[e] + mt * 128;
    int valid = counts[e] - mt * 128;
    if (valid <= 0) return;
    if (valid > 128) valid = 128;

    __shared__ __align__(16) unsigned short SM[4][8192];
    __shared__ int toks[128];

    const int tid = threadIdx.x;
    if (tid < 128) {
        int i = (tid < valid) ? tid : 0;
        toks[tid] = rowmap[grow + i] >> 1;
    }
    __syncthreads();

    const int wave = tid >> 6, lane = tid & 63;
    const int wm = wave >> 1, wn = wave & 1;
    const int quad = lane >> 4, l15 = lane & 15;

    // DMA mapping: 8 lanes/row, rows 128B-contiguous; global chunk pre-swizzled so the
    // linear LDS write lands at slot64(row, chunk) (m173 both-sides-or-neither rule)
    const unsigned short* ga[4];
    const unsigned short* gb[4];
    unsigned short* la[4];
    unsigned short* lb[4];
#pragma unroll
    for (int j = 0; j < 4; ++j) {
        int row = wave * 32 + j * 8 + (lane >> 3);
        int ch = (lane & 7) ^ ((lane >> 3) & 7);
        ga[j] = Xb + (size_t)toks[row] * DM + ch * 8;
        gb[j] = W1T + ((size_t)e * DF + nt * 128 + row) * DM + ch * 8;
        la[j] = &SM[0][(wave * 32 + j * 8) * 64];
        lb[j] = &SM[2][(wave * 32 + j * 8) * 64];
    }

    f32x4 acc[4][4] = {};

    STAGE(0, 0);
#pragma unroll 1
    for (int kt = 0; kt < 8; kt += 2) {
        if (kt + 1 < 8) { STAGE(1, (kt + 1) * 64); WAITN(8); } else { WAITN(0); }
        BAR();
        mfma_step(&SM[0][0], &SM[2][0], wm, wn, quad, l15, acc);
        BAR();
        if (kt + 2 < 8) { STAGE(0, (kt + 2) * 64); WAITN(8); } else { WAITN(0); }
        BAR();
        mfma_step(&SM[1][0], &SM[3][0], wm, wn, quad, l15, acc);
        BAR();
    }

    // ---- epilogue through LDS: bf16 C-tile [128][136], then coalesced 16B stores ----
    unsigned short* ep = &SM[0][0];
#pragma unroll
    for (int fm = 0; fm < 4; ++fm)
#pragma unroll
        for (int i = 0; i < 4; ++i) {
            int r = wm * 64 + fm * 16 + quad * 4 + i;
#pragma unroll
            for (int fn = 0; fn < 4; ++fn)
                ep[r * 136 + wn * 64 + fn * 16 + l15] = f2bf(gelu_fast(acc[fm][fn][i]));
        }
    __syncthreads();
    {
        const int rr0 = tid >> 4, ch = tid & 15;
#pragma unroll
        for (int it = 0; it < 8; ++it) {
            int r = it * 16 + rr0;
            uint4 v = *(const uint4*)&ep[r * 136 + ch * 8];
            *(uint4*)(H + (size_t)(grow + r) * DF + nt * 128 + ch * 8) = v;
        }
    }
}

// ------- GEMM2: out = H @ W2 (K=2048, no split-K, plain stores), BK=64 dbuf ----------
__launch_bounds__(256, 2)
__global__ void k_gemm2d(const unsigned short* __restrict__ H,
                         const unsigned short* __restrict__ W2T,
                         const int* __restrict__ counts, const int* __restrict__ opad,
                         const int* __restrict__ rowmap, float* __restrict__ out) {
    const int e = blockIdx.z, mt = blockIdx.y, nt = blockIdx.x;
    const int grow = opad[e] + mt * 128;
    int valid = counts[e] - mt * 128;
    if (valid <= 0) return;
    if (valid > 128) valid = 128;

    __shared__ __align__(16) unsigned short As[2][128 * 64];
    __shared__ __align__(16) unsigned short Bs[2][128 * 64];
    __shared__ int pairs[128];

    const int tid = threadIdx.x;
    if (tid < 128) pairs[tid] = (tid < valid) ? rowmap[grow + tid] : 0;
    __syncthreads();

    const int wave = tid >> 6, lane = tid & 63;
    const int wm = wave >> 1, wn = wave & 1;
    const int quad = lane >> 4, l15 = lane & 15;

    const unsigned short* ga[4];
    const unsigned short* gb[4];
    unsigned short* la[4];
    unsigned short* lb[4];
#pragma unroll
    for (int j = 0; j < 4; ++j) {
        int row = wave * 32 + j * 8 + (lane >> 3);
        int ch = (lane & 7) ^ ((lane >> 3) & 7);
        int rr = (row < valid) ? row : 0;  // clamp: never read unwritten H (r7 lesson)
        ga[j] = H + (size_t)(grow + rr) * DF + ch * 8;
        gb[j] = W2T + ((size_t)e * DM + nt * 128 + row) * DF + ch * 8;
        la[j] = &As[0][(wave * 32 + j * 8) * 64];
        lb[j] = &Bs[0][(wave * 32 + j * 8) * 64];
    }

    f32x4 acc[4][4] = {};

    STAGE(0, 0);
#pragma unroll 1
    for (int kt = 0; kt < 32; kt += 2) {
        if (kt + 1 < 32) { STAGE(1, (kt + 1) * 64); WAITN(8); } else { WAITN(0); }
        BAR();
        mfma_step(&As[0][0], &Bs[0][0], wm, wn, quad, l15, acc);
        BAR();
        if (kt + 2 < 32) { STAGE(0, (kt + 2) * 64); WAITN(8); } else { WAITN(0); }
        BAR();
        mfma_step(&As[1][0], &Bs[1][0], wm, wn, quad, l15, acc);
        BAR();
    }

#pragma unroll
    for (int fm = 0; fm < 4; ++fm) {
#pragma unroll
        for (int i = 0; i < 4; ++i) {
            int m_l = wm * 64 + fm * 16 + quad * 4 + i;
            if (m_l < valid) {
                float* orow = out + (size_t)pairs[m_l] * DM + nt * 128 + wn * 64;
#pragma unroll
                for (int fn = 0; fn < 4; ++fn)
                    orow[fn * 16 + l15] = acc[fm][fn][i];  // exactly-once: plain store
            }
        }
    }
}

extern "C" void kernel_launch(void* const* d_in, const int* in_sizes, int n_in,
                              void* d_out, int out_size, void* d_ws, size_t ws_size,
                              hipStream_t stream) {
    const float* X = (const float*)d_in[0];
    const int* sel = (const int*)d_in[1];
    const float* W1 = (const float*)d_in[3];
    const float* W2 = (const float*)d_in[4];
    float* out = (float*)d_out;
    float* loads_out = out + (size_t)NPAIR * DM;

    int* counts = (int*)d_ws;
    int* opad = counts + 16;
    int* rowmap = counts + 32;
    const size_t hbytes = (size_t)HCAP * DF * 2;
    const size_t xbytes = (size_t)NTOK * DM * 2;
    const size_t w1tbytes = (size_t)NE * DF * DM * 2;
    unsigned short* H = (unsigned short*)((char*)d_ws + 65536);
    unsigned short* Xb = (unsigned short*)((char*)d_ws + 65536 + hbytes);
    unsigned short* WT = (unsigned short*)((char*)d_ws + 65536 + hbytes + xbytes);

    // fused mode: separate W2T buffer -> W2 transpose folds into k_prep, no k_tw2 dispatch
    const bool fused = ws_size >= 65536 + hbytes + xbytes + 2 * w1tbytes;
    unsigned short* W2T = fused ? WT + w1tbytes / 2 : WT;

    hipLaunchKernelGGL(k_prep, dim3(fused ? 5121 : 3073), dim3(256), 0, stream,
                       X, Xb, W1, WT, W2, W2T, sel, counts, opad, rowmap, loads_out);
    hipLaunchKernelGGL(k_gemm1d, dim3(DF / 128, NPAIR / 128, NE), dim3(256), 0, stream,
                       Xb, WT, counts, opad, rowmap, H);
    if (!fused)
        hipLaunchKernelGGL(k_tw2, dim3(DM / 64, DF / 64, NE), dim3(256), 0, stream, W2, WT);
    hipLaunchKernelGGL(k_gemm2d, dim3(4, NPAIR / 128, NE), dim3(256), 0, stream,
                       H, W2T, counts, opad, rowmap, out);
}